// Round 1
// baseline (853.197 us; speedup 1.0000x reference)
//
#include <hip/hip_runtime.h>
#include <math.h>

#define B_   8
#define K_   8
#define BK_  64
#define L_   4096
#define D_   256
#define H_   512
#define S_   1024
#define M_   (BK_ * S_)   // 65536 rows
#define TM   16           // rows per block

// ---------------------------------------------------------------------------
// Kernel 1: per-batch argmax over event_time (first occurrence), as float.
// ---------------------------------------------------------------------------
__global__ __launch_bounds__(256) void limit_kernel(const float* __restrict__ et,
                                                    float* __restrict__ limitf) {
  __shared__ float sv[256];
  __shared__ int   si[256];
  const int b = blockIdx.x;
  const int t = threadIdx.x;
  const float* row = et + (size_t)b * L_;
  float best = -INFINITY;
  int bidx = 0;
  for (int i = t; i < L_; i += 256) {
    float v = row[i];
    if (v > best) { best = v; bidx = i; }   // strict > keeps earliest in-thread
  }
  sv[t] = best; si[t] = bidx;
  __syncthreads();
  for (int sft = 128; sft > 0; sft >>= 1) {
    if (t < sft) {
      float v2 = sv[t + sft]; int i2 = si[t + sft];
      if (v2 > sv[t] || (v2 == sv[t] && i2 < si[t])) { sv[t] = v2; si[t] = i2; }
    }
    __syncthreads();
  }
  if (t == 0) limitf[b] = (float)si[0];
}

// ---------------------------------------------------------------------------
// Kernel 2: fully fused MLP + pos/mask + lerp-gather for TM rows per block.
// LDS: xs[16][256] (16KB, reused for h2) + h1[16][512] (32KB) + posv = 48.3KB.
// Weights read straight from global: identical addresses across all 4 waves
// of a block -> L1/L2 resident.
// ---------------------------------------------------------------------------
__global__ __launch_bounds__(256) void fused_kernel(
    const float* __restrict__ X,  const float* __restrict__ W1,
    const float* __restrict__ b1, const float* __restrict__ W2,
    const float* __restrict__ b2, const float* __restrict__ W3,
    const float* __restrict__ limitf,
    float* __restrict__ out, float* __restrict__ maskv) {

  __shared__ float xs[TM * D_];   // input rows; later reused as h2
  __shared__ float h1[TM * H_];
  __shared__ float posv[TM];

  const int t   = threadIdx.x;
  const int blk = blockIdx.x;
  const int bk  = blk >> 6;            // 64 tiles of 16 rows per bk (S=1024)
  const int s0  = (blk & 63) << 4;
  const int bb  = bk >> 3;             // batch index b = bk / K
  const float limit = limitf[bb];
  const float* xbase = X + (size_t)bk * (L_ * D_);

  // ---- Phase 1: load xs rows (l = 2*s), 1024 float4s, coalesced ----
  #pragma unroll
  for (int i = 0; i < 4; ++i) {
    int f  = t + 256 * i;
    int r  = f >> 6;
    int c4 = f & 63;
    *(float4*)(xs + r * D_ + c4 * 4) =
        *(const float4*)(xbase + (size_t)(2 * (s0 + r)) * D_ + c4 * 4);
  }
  __syncthreads();

  const int tx = t & 63;
  const int ty = t >> 6;
  const int r0 = ty * 4;

  // ---- Phase 2: GEMM1 (16x512 = xs @ W1 + b1, relu), 4x8 per thread ----
  {
    const int n0 = tx * 8;
    float acc[4][8];
    float4 bb0 = *(const float4*)(b1 + n0);
    float4 bb1 = *(const float4*)(b1 + n0 + 4);
    #pragma unroll
    for (int i = 0; i < 4; ++i) {
      acc[i][0] = bb0.x; acc[i][1] = bb0.y; acc[i][2] = bb0.z; acc[i][3] = bb0.w;
      acc[i][4] = bb1.x; acc[i][5] = bb1.y; acc[i][6] = bb1.z; acc[i][7] = bb1.w;
    }
    #pragma unroll 2
    for (int k4 = 0; k4 < D_ / 4; ++k4) {
      float a_[4][4];
      #pragma unroll
      for (int i = 0; i < 4; ++i) {
        float4 v = *(const float4*)(xs + (r0 + i) * D_ + k4 * 4);
        a_[i][0] = v.x; a_[i][1] = v.y; a_[i][2] = v.z; a_[i][3] = v.w;
      }
      #pragma unroll
      for (int kk = 0; kk < 4; ++kk) {
        int k = k4 * 4 + kk;
        float4 w0 = *(const float4*)(W1 + (size_t)k * H_ + n0);
        float4 w1 = *(const float4*)(W1 + (size_t)k * H_ + n0 + 4);
        float bvals[8] = {w0.x, w0.y, w0.z, w0.w, w1.x, w1.y, w1.z, w1.w};
        #pragma unroll
        for (int i = 0; i < 4; ++i)
          #pragma unroll
          for (int j = 0; j < 8; ++j)
            acc[i][j] = fmaf(a_[i][kk], bvals[j], acc[i][j]);
      }
    }
    #pragma unroll
    for (int i = 0; i < 4; ++i)
      #pragma unroll
      for (int j = 0; j < 8; ++j)
        h1[(r0 + i) * H_ + n0 + j] = fmaxf(acc[i][j], 0.0f);
  }
  __syncthreads();

  // ---- Phase 3: GEMM2 (16x256 = h1 @ W2 + b2, relu), 4x4 per thread ----
  {
    const int n0 = tx * 4;
    float acc[4][4];
    float4 bbv = *(const float4*)(b2 + n0);
    #pragma unroll
    for (int i = 0; i < 4; ++i) {
      acc[i][0] = bbv.x; acc[i][1] = bbv.y; acc[i][2] = bbv.z; acc[i][3] = bbv.w;
    }
    #pragma unroll 2
    for (int k4 = 0; k4 < H_ / 4; ++k4) {
      float a_[4][4];
      #pragma unroll
      for (int i = 0; i < 4; ++i) {
        float4 v = *(const float4*)(h1 + (r0 + i) * H_ + k4 * 4);
        a_[i][0] = v.x; a_[i][1] = v.y; a_[i][2] = v.z; a_[i][3] = v.w;
      }
      #pragma unroll
      for (int kk = 0; kk < 4; ++kk) {
        int k = k4 * 4 + kk;
        float4 w = *(const float4*)(W2 + (size_t)k * D_ + n0);
        float bvals[4] = {w.x, w.y, w.z, w.w};
        #pragma unroll
        for (int i = 0; i < 4; ++i)
          #pragma unroll
          for (int j = 0; j < 4; ++j)
            acc[i][j] = fmaf(a_[i][kk], bvals[j], acc[i][j]);
      }
    }
    __syncthreads();   // xs reads all done (GEMM1); safe to overwrite with h2
    #pragma unroll
    for (int i = 0; i < 4; ++i) {
      float4 o;
      o.x = fmaxf(acc[i][0], 0.0f);
      o.y = fmaxf(acc[i][1], 0.0f);
      o.z = fmaxf(acc[i][2], 0.0f);
      o.w = fmaxf(acc[i][3], 0.0f);
      *(float4*)(xs + (r0 + i) * D_ + n0) = o;   // xs now holds h2
    }
  }
  __syncthreads();

  // ---- Phase 4: GEMM3 (offset = h2 @ W3), pos + mask ----
  {
    const int r = t >> 4;     // 16 rows, 16 lanes each
    const int j = t & 15;
    const float* hrow = xs + r * D_;
    float part = 0.0f;
    #pragma unroll
    for (int k = 0; k < 16; ++k)
      part = fmaf(hrow[j * 16 + k], W3[j * 16 + k], part);
    #pragma unroll
    for (int o = 8; o >= 1; o >>= 1)
      part += __shfl_xor(part, o, 64);
    if (j == 0) {
      float p = (float)(2 * (s0 + r)) + part;
      posv[r] = p;
      maskv[bk * S_ + s0 + r] = (p <= limit) ? 1.0f : 0.0f;
    }
  }
  __syncthreads();

  // ---- Phase 5: lerp gather + store, coalesced on D ----
  {
    const int c4 = t & 63;
    const int rg = t >> 6;
    #pragma unroll
    for (int rr = 0; rr < 4; ++rr) {
      int r = rg * 4 + rr;
      float p   = posv[r];
      float x0f = floorf(p);
      float w   = p - x0f;
      int i0 = (int)x0f;
      int i1 = i0 + 1;
      float v0 = (i0 >= 0 && i0 < L_) ? (1.0f - w) : 0.0f;
      float v1 = (i1 >= 0 && i1 < L_) ? w          : 0.0f;
      int ic0 = min(max(i0, 0), L_ - 1);
      int ic1 = min(max(i1, 0), L_ - 1);
      float4 g0 = *(const float4*)(xbase + (size_t)ic0 * D_ + c4 * 4);
      float4 g1 = *(const float4*)(xbase + (size_t)ic1 * D_ + c4 * 4);
      float4 o;
      o.x = v0 * g0.x + v1 * g1.x;
      o.y = v0 * g0.y + v1 * g1.y;
      o.z = v0 * g0.z + v1 * g1.z;
      o.w = v0 * g0.w + v1 * g1.w;
      *(float4*)(out + (size_t)(bk * S_ + s0 + r) * D_ + c4 * 4) = o;
    }
  }
}

// ---------------------------------------------------------------------------
extern "C" void kernel_launch(void* const* d_in, const int* in_sizes, int n_in,
                              void* d_out, int out_size, void* d_ws, size_t ws_size,
                              hipStream_t stream) {
  const float* X  = (const float*)d_in[0];
  const float* et = (const float*)d_in[1];
  const float* W1 = (const float*)d_in[2];
  const float* b1 = (const float*)d_in[3];
  const float* W2 = (const float*)d_in[4];
  const float* b2 = (const float*)d_in[5];
  const float* W3 = (const float*)d_in[6];
  float* out    = (float*)d_out;
  float* maskv  = out + (size_t)M_ * D_;
  float* limitf = (float*)d_ws;   // 8 floats

  limit_kernel<<<B_, 256, 0, stream>>>(et, limitf);
  fused_kernel<<<M_ / TM, 256, 0, stream>>>(X, W1, b1, W2, b2, W3, limitf, out, maskv);
}

// Round 2
// 471.146 us; speedup vs baseline: 1.8109x; 1.8109x over previous
//
#include <hip/hip_runtime.h>
#include <math.h>

#define B_   8
#define K_   8
#define L_   4096
#define D_   256    // K of GEMM1, N of GEMM2
#define H_   512    // N of GEMM1, K of GEMM2
#define S_   1024
#define M_   65536
#define MAXF 4096

typedef _Float16 half8  __attribute__((ext_vector_type(8)));
typedef float    floatx4 __attribute__((ext_vector_type(4)));

// ws layout (bytes):
#define WS_LIMIT   0                       // float[8]
#define WS_COUNTER 64                      // int
#define WS_FLAGS   128                     // int[MAXF]
#define WS_W1T     65536                   // fp16 [512][256] = 256KB
#define WS_W2T     (65536 + H_*D_*2)       // fp16 [256][512] = 256KB

// ---------------------------------------------------------------------------
// Prep: blocks 0..1023 convert W1->W1T fp16, W2->W2T fp16 (transposed);
// blocks 1024..1031 per-batch argmax (first occurrence); block 1032 zeros ctr.
// ---------------------------------------------------------------------------
__global__ __launch_bounds__(256) void prep_kernel(const float* __restrict__ et,
                                                   const float* __restrict__ W1,
                                                   const float* __restrict__ W2,
                                                   char* __restrict__ ws) {
  __shared__ float sv[256];
  __shared__ int   si[256];
  const int blk = blockIdx.x;
  const int t   = threadIdx.x;
  if (blk < 1024) {
    int e = blk * 256 + t;               // 0..262143
    if (e < H_ * D_) {                   // W1T[n][k] = W1[k][n]
      int n = e >> 8, k = e & 255;
      ((_Float16*)(ws + WS_W1T))[e] = (_Float16)W1[(size_t)k * H_ + n];
    } else {
      int e2 = e - H_ * D_;              // W2T[n][k] = W2[k][n]
      int n = e2 >> 9, k = e2 & 511;
      ((_Float16*)(ws + WS_W2T))[e2] = (_Float16)W2[(size_t)k * D_ + n];
    }
  } else if (blk < 1032) {
    int b = blk - 1024;
    const float* row = et + (size_t)b * L_;
    float best = -INFINITY; int bidx = 0;
    for (int i = t; i < L_; i += 256) {
      float v = row[i];
      if (v > best) { best = v; bidx = i; }
    }
    sv[t] = best; si[t] = bidx;
    __syncthreads();
    for (int sft = 128; sft > 0; sft >>= 1) {
      if (t < sft) {
        float v2 = sv[t + sft]; int i2 = si[t + sft];
        if (v2 > sv[t] || (v2 == sv[t] && i2 < si[t])) { sv[t] = v2; si[t] = i2; }
      }
      __syncthreads();
    }
    if (t == 0) ((float*)(ws + WS_LIMIT))[b] = (float)si[0];
  } else {
    if (t == 0) *(int*)(ws + WS_COUNTER) = 0;
  }
}

// ---------------------------------------------------------------------------
// GEMM1: h1 = relu(Xs @ W1 + b1), M=65536 N=512 K=256, fp16 MFMA.
// h1 stored fp16 [m][512] INTO d_out (aliased; each row read only by the
// gemm2 block that later overwrites those exact bytes).
// Block tile 64x256 (grid: n fastest for A L2 reuse), wave tile 32x128.
// ---------------------------------------------------------------------------
__global__ __launch_bounds__(256) void gemm1_kernel(
    const float* __restrict__ X, const char* __restrict__ ws,
    const float* __restrict__ b1, _Float16* __restrict__ h1out) {
  __shared__ _Float16 As[64 * 32];
  __shared__ _Float16 Bs[256 * 32];
  const _Float16* W1T = (const _Float16*)(ws + WS_W1T);

  const int t    = threadIdx.x;
  const int blk  = blockIdx.x;          // 2048
  const int n0b  = (blk & 1) * 256;
  const int m0   = (blk >> 1) * 64;
  const int w    = t >> 6, lane = t & 63;
  const int lr   = lane & 15, quad = lane >> 4;
  const int rowoff = (w & 1) * 32, coloff = (w >> 1) * 128;

  floatx4 acc[2][8] = {};

  // A staging role: thread -> (row r, quarter q)
  const int r = t >> 2, q = t & 3;
  const int m  = m0 + r;
  const int bk = m >> 10, s = m & 1023;
  const float* xrow = X + ((size_t)bk * L_ + 2 * s) * D_;

  for (int k0 = 0; k0 < D_; k0 += 32) {
    __syncthreads();
    { // stage A: 64x32 fp32 -> fp16
      float4 v0 = *(const float4*)(xrow + k0 + q * 8);
      float4 v1 = *(const float4*)(xrow + k0 + q * 8 + 4);
      half8 h;
      h[0]=(_Float16)v0.x; h[1]=(_Float16)v0.y; h[2]=(_Float16)v0.z; h[3]=(_Float16)v0.w;
      h[4]=(_Float16)v1.x; h[5]=(_Float16)v1.y; h[6]=(_Float16)v1.z; h[7]=(_Float16)v1.w;
      *(half8*)(&As[r * 32 + q * 8]) = h;
    }
    { // stage B: 256x32 fp16 from W1T (rows n0b..n0b+255, k-contig)
      #pragma unroll
      for (int c = 0; c < 4; ++c) {
        int n = w * 64 + c * 16 + (lane >> 2);
        *(uint4*)((char*)Bs + n * 64 + (lane & 3) * 16) =
            *(const uint4*)(W1T + (size_t)(n0b + n) * D_ + k0 + (lane & 3) * 8);
      }
    }
    __syncthreads();
    half8 af[2], bf[8];
    #pragma unroll
    for (int mt = 0; mt < 2; ++mt)
      af[mt] = *(const half8*)&As[(rowoff + mt * 16 + lr) * 32 + quad * 8];
    #pragma unroll
    for (int nt = 0; nt < 8; ++nt)
      bf[nt] = *(const half8*)&Bs[(coloff + nt * 16 + lr) * 32 + quad * 8];
    #pragma unroll
    for (int mt = 0; mt < 2; ++mt)
      #pragma unroll
      for (int nt = 0; nt < 8; ++nt)
        acc[mt][nt] = __builtin_amdgcn_mfma_f32_16x16x32_f16(af[mt], bf[nt], acc[mt][nt], 0, 0, 0);
  }

  // epilogue: relu(acc+b1) -> fp16 h1
  #pragma unroll
  for (int nt = 0; nt < 8; ++nt) {
    int col = n0b + coloff + nt * 16 + lr;
    float bias = b1[col];
    #pragma unroll
    for (int mt = 0; mt < 2; ++mt) {
      int rowb = m0 + rowoff + mt * 16 + quad * 4;
      #pragma unroll
      for (int rg = 0; rg < 4; ++rg) {
        float v = acc[mt][nt][rg] + bias;
        h1out[(size_t)(rowb + rg) * H_ + col] = (_Float16)(v > 0.f ? v : 0.f);
      }
    }
  }
}

// ---------------------------------------------------------------------------
// GEMM2 fused: h2 = relu(h1 @ W2 + b2); offset = h2 @ W3; pos/mask/flag;
// lerp gather -> out. M=65536 N=256 K=512. A read from h1 (aliased w/ out).
// ---------------------------------------------------------------------------
__global__ __launch_bounds__(256) void gemm2_kernel(
    const float* __restrict__ X, char* __restrict__ ws,
    const float* __restrict__ b2, const float* __restrict__ W3,
    float* out, float* maskv) {
  __shared__ _Float16 As[64 * 32];
  __shared__ _Float16 Bs[256 * 32];
  __shared__ float psum[2][64];
  __shared__ float posl[64];
  const _Float16* W2T    = (const _Float16*)(ws + WS_W2T);
  const float*    limitf = (const float*)(ws + WS_LIMIT);
  int*            counter = (int*)(ws + WS_COUNTER);
  int*            flags   = (int*)(ws + WS_FLAGS);
  const _Float16* h1 = (const _Float16*)out;   // ALIASED on purpose

  const int t    = threadIdx.x;
  const int m0   = blockIdx.x * 64;     // 1024 blocks
  const int w    = t >> 6, lane = t & 63;
  const int lr   = lane & 15, quad = lane >> 4;
  const int rowoff = (w & 1) * 32, coloff = (w >> 1) * 128;

  floatx4 acc[2][8] = {};

  for (int k0 = 0; k0 < H_; k0 += 32) {
    __syncthreads();
    { // stage A from h1 (fp16): 64x32
      int rr = t >> 2, qq = t & 3;
      *(uint4*)((char*)As + rr * 64 + qq * 16) =
          *(const uint4*)(h1 + (size_t)(m0 + rr) * H_ + k0 + qq * 8);
    }
    { // stage B from W2T: 256x32
      #pragma unroll
      for (int c = 0; c < 4; ++c) {
        int n = w * 64 + c * 16 + (lane >> 2);
        *(uint4*)((char*)Bs + n * 64 + (lane & 3) * 16) =
            *(const uint4*)(W2T + (size_t)n * H_ + k0 + (lane & 3) * 8);
      }
    }
    __syncthreads();
    half8 af[2], bf[8];
    #pragma unroll
    for (int mt = 0; mt < 2; ++mt)
      af[mt] = *(const half8*)&As[(rowoff + mt * 16 + lr) * 32 + quad * 8];
    #pragma unroll
    for (int nt = 0; nt < 8; ++nt)
      bf[nt] = *(const half8*)&Bs[(coloff + nt * 16 + lr) * 32 + quad * 8];
    #pragma unroll
    for (int mt = 0; mt < 2; ++mt)
      #pragma unroll
      for (int nt = 0; nt < 8; ++nt)
        acc[mt][nt] = __builtin_amdgcn_mfma_f32_16x16x32_f16(af[mt], bf[nt], acc[mt][nt], 0, 0, 0);
  }

  // epilogue: relu + offset partials (fp32)
  float part[2][4] = {{0,0,0,0},{0,0,0,0}};
  #pragma unroll
  for (int nt = 0; nt < 8; ++nt) {
    int col = coloff + nt * 16 + lr;
    float bias = b2[col];
    float w3   = W3[col];
    #pragma unroll
    for (int mt = 0; mt < 2; ++mt)
      #pragma unroll
      for (int rg = 0; rg < 4; ++rg) {
        float h2 = acc[mt][nt][rg] + bias;
        h2 = h2 > 0.f ? h2 : 0.f;
        part[mt][rg] = fmaf(h2, w3, part[mt][rg]);
      }
  }
  #pragma unroll
  for (int mt = 0; mt < 2; ++mt)
    #pragma unroll
    for (int rg = 0; rg < 4; ++rg) {
      float p = part[mt][rg];
      p += __shfl_xor(p, 1, 64);
      p += __shfl_xor(p, 2, 64);
      p += __shfl_xor(p, 4, 64);
      p += __shfl_xor(p, 8, 64);
      if (lr == 0) psum[w >> 1][rowoff + mt * 16 + quad * 4 + rg] = p;
    }
  __syncthreads();
  if (t < 64) {
    int   mrow  = m0 + t;
    float off   = psum[0][t] + psum[1][t];
    int   s     = mrow & 1023;
    float pos   = (float)(2 * s) + off;
    float limit = limitf[mrow >> 13];
    maskv[mrow] = (pos <= limit) ? 1.f : 0.f;
    posl[t] = pos;
    float d = pos - limit;
    if (d < 0.5f && d > -0.5f) {            // near-boundary -> exact fixup later
      int idx = atomicAdd(counter, 1);
      if (idx < MAXF) flags[idx] = mrow;
    }
  }
  __syncthreads();
  { // lerp gather -> out (overwrites this block's h1 bytes; all reads done)
    const int c4 = t & 63, rg = t >> 6;
    const int bk = m0 >> 10;
    const float* xbase = X + (size_t)bk * (L_ * D_);
    #pragma unroll 4
    for (int rr = 0; rr < 16; ++rr) {
      int   rI = rg * 16 + rr;
      float p  = posl[rI];
      float x0f = floorf(p);
      float ww  = p - x0f;
      int i0 = (int)x0f, i1 = i0 + 1;
      float v0 = (i0 >= 0 && i0 < L_) ? (1.f - ww) : 0.f;
      float v1 = (i1 >= 0 && i1 < L_) ? ww : 0.f;
      int ic0 = min(max(i0, 0), L_ - 1), ic1 = min(max(i1, 0), L_ - 1);
      float4 g0 = *(const float4*)(xbase + (size_t)ic0 * D_ + c4 * 4);
      float4 g1 = *(const float4*)(xbase + (size_t)ic1 * D_ + c4 * 4);
      float4 o;
      o.x = v0 * g0.x + v1 * g1.x;
      o.y = v0 * g0.y + v1 * g1.y;
      o.z = v0 * g0.z + v1 * g1.z;
      o.w = v0 * g0.w + v1 * g1.w;
      *(float4*)(out + (size_t)(m0 + rI) * D_ + c4 * 4) = o;
    }
  }
}

// ---------------------------------------------------------------------------
// Fixup: exact fp32 recompute of offset for flagged near-boundary rows.
// ---------------------------------------------------------------------------
__global__ __launch_bounds__(256) void fixup_kernel(
    const float* __restrict__ X,  const float* __restrict__ W1,
    const float* __restrict__ b1, const float* __restrict__ W2,
    const float* __restrict__ b2, const float* __restrict__ W3,
    const char* __restrict__ ws, float* __restrict__ maskv) {
  __shared__ float xs[256];
  __shared__ float h1s[512];
  __shared__ float red[4];
  const float* limitf  = (const float*)(ws + WS_LIMIT);
  const int*   counter = (const int*)(ws + WS_COUNTER);
  const int*   flags   = (const int*)(ws + WS_FLAGS);
  const int t = threadIdx.x;
  const int cnt = min(*counter, MAXF);
  for (int fi = blockIdx.x; fi < cnt; fi += 64) {
    int mrow = flags[fi];
    int bk = mrow >> 10, s = mrow & 1023;
    const float* xrow = X + ((size_t)bk * L_ + 2 * s) * D_;
    xs[t] = xrow[t];
    __syncthreads();
    #pragma unroll
    for (int jj = 0; jj < 2; ++jj) {
      int j = t + jj * 256;
      float a = b1[j];
      for (int d = 0; d < 256; ++d)
        a = fmaf(xs[d], W1[(size_t)d * H_ + j], a);
      h1s[j] = a > 0.f ? a : 0.f;
    }
    __syncthreads();
    {
      float a = b2[t];
      for (int e = 0; e < 512; ++e)
        a = fmaf(h1s[e], W2[(size_t)e * D_ + t], a);
      float h2 = a > 0.f ? a : 0.f;
      float pp = h2 * W3[t];
      #pragma unroll
      for (int o = 32; o >= 1; o >>= 1) pp += __shfl_xor(pp, o, 64);
      if ((t & 63) == 0) red[t >> 6] = pp;
    }
    __syncthreads();
    if (t == 0) {
      float off   = red[0] + red[1] + red[2] + red[3];
      float pos   = (float)(2 * s) + off;
      float limit = limitf[mrow >> 13];
      maskv[mrow] = (pos <= limit) ? 1.f : 0.f;
    }
    __syncthreads();
  }
}

// ---------------------------------------------------------------------------
extern "C" void kernel_launch(void* const* d_in, const int* in_sizes, int n_in,
                              void* d_out, int out_size, void* d_ws, size_t ws_size,
                              hipStream_t stream) {
  const float* X  = (const float*)d_in[0];
  const float* et = (const float*)d_in[1];
  const float* W1 = (const float*)d_in[2];
  const float* b1 = (const float*)d_in[3];
  const float* W2 = (const float*)d_in[4];
  const float* b2 = (const float*)d_in[5];
  const float* W3 = (const float*)d_in[6];
  float* out   = (float*)d_out;
  float* maskv = out + (size_t)M_ * D_;
  char*  ws    = (char*)d_ws;

  prep_kernel <<<1033, 256, 0, stream>>>(et, W1, W2, ws);
  gemm1_kernel<<<2048, 256, 0, stream>>>(X, ws, b1, (_Float16*)d_out);
  gemm2_kernel<<<1024, 256, 0, stream>>>(X, ws, b2, W3, out, maskv);
  fixup_kernel<<<64,   256, 0, stream>>>(X, W1, b1, W2, b2, W3, ws, maskv);
}